// Round 1
// baseline (1957.616 us; speedup 1.0000x reference)
//
#include <hip/hip_runtime.h>
#include <cfloat>

#define DEV __device__ __forceinline__

DEV unsigned enc_ord(float f) {
    unsigned u = __float_as_uint(f);
    return (u & 0x80000000u) ? ~u : (u | 0x80000000u);
}

// ---------------- CSR build ----------------
__global__ __launch_bounds__(256) void k_hist(const int* __restrict__ ei, int* __restrict__ deg, int E) {
    int e = blockIdx.x * 256 + threadIdx.x;
    if (e < E) atomicAdd(&deg[ei[E + e]], 1);
}

__global__ __launch_bounds__(256) void k_scan1(const int* __restrict__ deg, int* __restrict__ rowptr,
                                               int* __restrict__ bsums, int n) {
    __shared__ int sh[256];
    int tid = threadIdx.x;
    int base = blockIdx.x * 1024 + tid * 4;
    int v0 = (base + 0 < n) ? deg[base + 0] : 0;
    int v1 = (base + 1 < n) ? deg[base + 1] : 0;
    int v2 = (base + 2 < n) ? deg[base + 2] : 0;
    int v3 = (base + 3 < n) ? deg[base + 3] : 0;
    int tsum = v0 + v1 + v2 + v3;
    sh[tid] = tsum; __syncthreads();
    for (int off = 1; off < 256; off <<= 1) {
        int x = (tid >= off) ? sh[tid - off] : 0; __syncthreads();
        sh[tid] += x; __syncthreads();
    }
    int excl = sh[tid] - tsum;
    if (tid == 255) bsums[blockIdx.x] = sh[255];
    int run = excl;
    if (base + 0 < n) rowptr[base + 0] = run; run += v0;
    if (base + 1 < n) rowptr[base + 1] = run; run += v1;
    if (base + 2 < n) rowptr[base + 2] = run; run += v2;
    if (base + 3 < n) rowptr[base + 3] = run;
}

__global__ __launch_bounds__(256) void k_scan2(int* __restrict__ bsums, int nb) {
    __shared__ int sh[256];
    int tid = threadIdx.x;
    int v = (tid < nb) ? bsums[tid] : 0;
    sh[tid] = v; __syncthreads();
    for (int off = 1; off < 256; off <<= 1) {
        int x = (tid >= off) ? sh[tid - off] : 0; __syncthreads();
        sh[tid] += x; __syncthreads();
    }
    if (tid < nb) bsums[tid] = sh[tid] - v;
}

__global__ __launch_bounds__(256) void k_scan_add(const int* __restrict__ deg, int* __restrict__ rowptr,
                                                  const int* __restrict__ bsums, int* __restrict__ cursor,
                                                  float* __restrict__ dinv, int n, int E) {
    int i = blockIdx.x * 256 + threadIdx.x;
    if (i == 0) rowptr[n] = E;
    if (i < n) {
        int rp = rowptr[i] + bsums[i >> 10];
        rowptr[i] = rp;
        cursor[i] = rp;
        dinv[i] = rsqrtf((float)deg[i] + 1.0f);  // +1 self-loop
    }
}

__global__ __launch_bounds__(256) void k_fill(const int* __restrict__ ei, int* __restrict__ cursor,
                                              int* __restrict__ colA, int E) {
    int e = blockIdx.x * 256 + threadIdx.x;
    if (e < E) {
        int s = ei[e], d = ei[E + e];
        int p = atomicAdd(&cursor[d], 1);
        colA[p] = s;
    }
}

// ---------------- dense matmul: out[r,c] = (dinv[r]?) * sum_k in[r,k]*W[k,c] (+bias) ----------------
// in: [n, K] packed. W: [K, ldw], cols [colOff, colOff+COUT). out: [n, ldo] at colOff.
template <int K, int COUT, bool SCALE, bool BIAS>
__global__ __launch_bounds__(256) void k_mm(const float* __restrict__ in, const float* __restrict__ W,
                                            const float* __restrict__ bias, const float* __restrict__ dinv,
                                            float* __restrict__ out, int n, int ldw, int ldo, int colOff) {
    constexpr int CG = COUT / 4;          // threads spanning the columns (4 cols each)
    constexpr int SLOTS = 256 / CG;       // row slots
    constexpr int TR = (K == 128) ? 32 : 64;  // rows per block (LDS budget)
    constexpr int RPT = TR / SLOTS;       // rows per thread
    constexpr int KP = K + 1;             // padded lead dim (bank-conflict-free)
    __shared__ __align__(16) float sW[K * COUT];
    __shared__ float sH[TR * KP];
    const int tid = threadIdx.x;
    const int rowBase = blockIdx.x * TR;

    constexpr int W4 = COUT / 4;
    for (int idx = tid; idx < K * W4; idx += 256) {
        int k = idx / W4, c4 = idx - k * W4;
        ((float4*)sW)[idx] = *(const float4*)(W + (size_t)k * ldw + colOff + c4 * 4);
    }
    const float4* inp4 = (const float4*)(in + (size_t)rowBase * K);
    for (int idx = tid; idx < TR * K / 4; idx += 256) {
        int elem = idx * 4;
        int r = elem / K, k = elem - r * K;
        float4 h = (rowBase + r < n) ? inp4[idx] : make_float4(0.f, 0.f, 0.f, 0.f);
        float* d = &sH[r * KP + k];
        d[0] = h.x; d[1] = h.y; d[2] = h.z; d[3] = h.w;
    }
    __syncthreads();

    const int cg = tid % CG;
    const int slot = tid / CG;
    float4 acc[RPT];
#pragma unroll
    for (int j = 0; j < RPT; ++j) acc[j] = make_float4(0.f, 0.f, 0.f, 0.f);
#pragma unroll 4
    for (int k = 0; k < K; ++k) {
        float4 w = *(const float4*)&sW[k * COUT + cg * 4];
#pragma unroll
        for (int j = 0; j < RPT; ++j) {
            float h = sH[(slot + j * SLOTS) * KP + k];
            acc[j].x += h * w.x; acc[j].y += h * w.y; acc[j].z += h * w.z; acc[j].w += h * w.w;
        }
    }
#pragma unroll
    for (int j = 0; j < RPT; ++j) {
        int r = rowBase + slot + j * SLOTS;
        if (r < n) {
            float4 o = acc[j];
            if (SCALE) { float di = dinv[r]; o.x *= di; o.y *= di; o.z *= di; o.w *= di; }
            if (BIAS) {
                float4 b = *(const float4*)(bias + colOff + cg * 4);
                o.x += b.x; o.y += b.y; o.z += b.z; o.w += b.w;
            }
            *(float4*)(out + (size_t)r * ldo + colOff + cg * 4) = o;
        }
    }
}

// ---------------- aggregation (pull, one wave per row) ----------------
// s_i = sum_{e in in(i)} g[col[e]] + g[i]
// MODE 0: out = relu(dinv*s + b)          (enc1, conv1, conv2)
// MODE 1: out = dinv*s + b                (enc2)
// MODE 2: out = dinv*relu(dinv*s + b)     (conv3 -> scaled for SG chain)
// MODE 3: out = dinv^2*s                  (SG propagates 1-3)
// MODE 4: out = dinv*s                    (SG propagate 4)
template <int WIDTH, int MODE>
__global__ __launch_bounds__(256) void k_agg(const float* __restrict__ g, const int* __restrict__ rowptr,
                                             const int* __restrict__ col, const float* __restrict__ dinv,
                                             const float* __restrict__ bias, float* __restrict__ out, int n) {
    constexpr int VEC = WIDTH / 64;
    int wid = (blockIdx.x * 256 + threadIdx.x) >> 6;
    int lane = threadIdx.x & 63;
    if (wid >= n) return;
    const int off = lane * VEC;
    float a0, a1 = 0.f;
    {
        const float* p = g + (size_t)wid * WIDTH + off;
        if (VEC == 1) a0 = *p;
        else { float2 v = *(const float2*)p; a0 = v.x; a1 = v.y; }
    }
    int e0 = rowptr[wid], e1 = rowptr[wid + 1];
    int e = e0;
    for (; e + 4 <= e1; e += 4) {
        int c0 = col[e], c1 = col[e + 1], c2 = col[e + 2], c3 = col[e + 3];
        const float* p0 = g + (size_t)c0 * WIDTH + off;
        const float* p1 = g + (size_t)c1 * WIDTH + off;
        const float* p2 = g + (size_t)c2 * WIDTH + off;
        const float* p3 = g + (size_t)c3 * WIDTH + off;
        if (VEC == 1) {
            float x0 = *p0, x1 = *p1, x2 = *p2, x3 = *p3;
            a0 += (x0 + x1) + (x2 + x3);
        } else {
            float2 x0 = *(const float2*)p0, x1 = *(const float2*)p1;
            float2 x2 = *(const float2*)p2, x3 = *(const float2*)p3;
            a0 += (x0.x + x1.x) + (x2.x + x3.x);
            a1 += (x0.y + x1.y) + (x2.y + x3.y);
        }
    }
    for (; e < e1; ++e) {
        const float* p = g + (size_t)col[e] * WIDTH + off;
        if (VEC == 1) a0 += *p;
        else { float2 v = *(const float2*)p; a0 += v.x; a1 += v.y; }
    }
    float di = dinv[wid];
    if (MODE == 0) {
        a0 = fmaxf(di * a0 + bias[off], 0.f);
        if (VEC == 2) a1 = fmaxf(di * a1 + bias[off + 1], 0.f);
    } else if (MODE == 1) {
        a0 = di * a0 + bias[off];
        if (VEC == 2) a1 = di * a1 + bias[off + 1];
    } else if (MODE == 2) {
        a0 = di * fmaxf(di * a0 + bias[off], 0.f);
        if (VEC == 2) a1 = di * fmaxf(di * a1 + bias[off + 1], 0.f);
    } else if (MODE == 3) {
        float d2 = di * di;
        a0 *= d2; a1 *= d2;
    } else {
        a0 *= di; a1 *= di;
    }
    if (VEC == 1) out[(size_t)wid * 64 + lane] = a0;
    else *(float2*)(out + (size_t)wid * 128 + off) = make_float2(a0, a1);
}

// ---------------- global max pool (batch sorted) ----------------
__global__ __launch_bounds__(64) void k_pool(const float* __restrict__ z, const int* __restrict__ batch,
                                             unsigned* __restrict__ pooled, int n) {
    constexpr int ROWS = 128;
    int lane = threadIdx.x;
    int r0 = blockIdx.x * ROWS;
    if (r0 >= n) return;
    int r1 = min(r0 + ROWS, n);
    int cur = batch[r0];
    float m = -FLT_MAX;
    for (int r = r0; r < r1; ++r) {
        int b = batch[r];
        float v = z[(size_t)r * 64 + lane];
        if (b != cur) {
            atomicMax(&pooled[cur * 64 + lane], enc_ord(m));
            cur = b; m = v;
        } else {
            m = fmaxf(m, v);
        }
    }
    atomicMax(&pooled[cur * 64 + lane], enc_ord(m));
}

// ---------------- final MLP: one thread per graph ----------------
__global__ __launch_bounds__(256) void k_mlp(const unsigned* __restrict__ pooled,
                                             const float* __restrict__ fc1w, const float* __restrict__ fc1b,
                                             const float* __restrict__ fc2w, const float* __restrict__ fc2b,
                                             const float* __restrict__ cpdw, const float* __restrict__ cpdb,
                                             const float* __restrict__ combw, const float* __restrict__ combb,
                                             float* __restrict__ out, int G) {
    __shared__ float s1[64 * 32], s2[32 * 16], sb1[32], sb2[16], scw[16], sow[16], shead[2];
    int tid = threadIdx.x;
    for (int i = tid; i < 2048; i += 256) s1[i] = fc1w[i];
    for (int i = tid; i < 512; i += 256) s2[i] = fc2w[i];
    if (tid < 32) sb1[tid] = fc1b[tid];
    if (tid < 16) { sb2[tid] = fc2b[tid]; scw[tid] = cpdw[tid]; sow[tid] = combw[tid]; }
    if (tid == 0) { shead[0] = cpdb[0]; shead[1] = combb[0]; }
    __syncthreads();
    if (tid < G) {
        float h0[64];
#pragma unroll
        for (int k = 0; k < 64; ++k) {
            unsigned u = pooled[tid * 64 + k];
            unsigned b = (u & 0x80000000u) ? (u & 0x7fffffffu) : ~u;
            h0[k] = __uint_as_float(b);
        }
        float h1[32];
#pragma unroll
        for (int j = 0; j < 32; ++j) {
            float a = sb1[j];
#pragma unroll
            for (int k = 0; k < 64; ++k) a += h0[k] * s1[k * 32 + j];
            h1[j] = fmaxf(a, 0.f);
        }
        float h2[16];
#pragma unroll
        for (int j = 0; j < 16; ++j) {
            float a = sb2[j];
#pragma unroll
            for (int k = 0; k < 32; ++k) a += h1[k] * s2[k * 16 + j];
            h2[j] = fmaxf(a, 0.f);
        }
        float c1 = shead[0], c2 = shead[1];
#pragma unroll
        for (int k = 0; k < 16; ++k) { c1 += h2[k] * scw[k]; c2 += h2[k] * sow[k]; }
        out[tid] = c1;
        out[G + tid] = c2;
    }
}

extern "C" void kernel_launch(void* const* d_in, const int* in_sizes, int n_in,
                              void* d_out, int out_size, void* d_ws, size_t ws_size,
                              hipStream_t stream) {
    const float* x      = (const float*)d_in[0];
    const int*   ei     = (const int*)d_in[1];
    const int*   batch  = (const int*)d_in[2];
    const float* enc_w1 = (const float*)d_in[3];
    const float* enc_b1 = (const float*)d_in[4];
    const float* enc_w2 = (const float*)d_in[5];
    const float* enc_b2 = (const float*)d_in[6];
    const float* w1 = (const float*)d_in[7];   const float* b1 = (const float*)d_in[8];
    const float* w2 = (const float*)d_in[9];   const float* b2 = (const float*)d_in[10];
    const float* w3 = (const float*)d_in[11];  const float* b3 = (const float*)d_in[12];
    const float* sgw = (const float*)d_in[13]; const float* sgb = (const float*)d_in[14];
    const float* fc1w = (const float*)d_in[15]; const float* fc1b = (const float*)d_in[16];
    const float* fc2w = (const float*)d_in[17]; const float* fc2b = (const float*)d_in[18];
    const float* cpdw = (const float*)d_in[19]; const float* cpdb = (const float*)d_in[20];
    const float* combw = (const float*)d_in[21]; const float* combb = (const float*)d_in[22];

    const int n = in_sizes[0] / 128;
    const int E = in_sizes[1] / 2;
    const int G = out_size / 2;
    float* outp = (float*)d_out;

    // workspace layout
    char* p = (char*)d_ws;
    auto alloc = [&](size_t bytes) -> char* {
        char* r = p;
        p += (bytes + 255) & ~(size_t)255;
        return r;
    };
    int* deg       = (int*)alloc((size_t)n * 4);
    int* rowptr    = (int*)alloc((size_t)(n + 1) * 4);
    int* cursor    = (int*)alloc((size_t)n * 4);
    float* dinv    = (float*)alloc((size_t)n * 4);
    int* bsums     = (int*)alloc(1024 * 4);
    int* colA      = (int*)alloc((size_t)E * 4);
    unsigned* pooled = (unsigned*)alloc((size_t)G * 64 * 4);
    float* A       = (float*)alloc((size_t)n * 128 * 4);
    float* B       = (float*)alloc((size_t)n * 128 * 4);

    hipMemsetAsync(deg, 0, (size_t)n * 4, stream);
    hipMemsetAsync(pooled, 0, (size_t)G * 64 * 4, stream);

    const int gE = (E + 255) / 256;
    const int nb = (n + 1023) / 1024;
    k_hist<<<gE, 256, 0, stream>>>(ei, deg, E);
    k_scan1<<<nb, 256, 0, stream>>>(deg, rowptr, bsums, n);
    k_scan2<<<1, 256, 0, stream>>>(bsums, nb);
    k_scan_add<<<(n + 255) / 256, 256, 0, stream>>>(deg, rowptr, bsums, cursor, dinv, n, E);
    k_fill<<<gE, 256, 0, stream>>>(ei, cursor, colA, E);

    const int gm128 = (n + 31) / 32;  // TR=32 for K=128
    const int gm64  = (n + 63) / 64;  // TR=64 for K=64
    const int ga    = (n + 3) / 4;    // 4 waves/block, 1 row/wave

    // encoder layer 1: x[N,128] @ enc_w1[128,128] (two column halves), then propagate+relu
    k_mm<128, 64, true, false><<<gm128, 256, 0, stream>>>(x, enc_w1, nullptr, dinv, A, n, 128, 128, 0);
    k_mm<128, 64, true, false><<<gm128, 256, 0, stream>>>(x, enc_w1, nullptr, dinv, A, n, 128, 128, 64);
    k_agg<128, 0><<<ga, 256, 0, stream>>>(A, rowptr, colA, dinv, enc_b1, B, n);
    // encoder layer 2: [N,128] -> [N,64], propagate (no relu)
    k_mm<128, 64, true, false><<<gm128, 256, 0, stream>>>(B, enc_w2, nullptr, dinv, A, n, 64, 64, 0);
    k_agg<64, 1><<<ga, 256, 0, stream>>>(A, rowptr, colA, dinv, enc_b2, B, n);
    // conv1, conv2 (relu)
    k_mm<64, 64, true, false><<<gm64, 256, 0, stream>>>(B, w1, nullptr, dinv, A, n, 64, 64, 0);
    k_agg<64, 0><<<ga, 256, 0, stream>>>(A, rowptr, colA, dinv, b1, B, n);
    k_mm<64, 64, true, false><<<gm64, 256, 0, stream>>>(B, w2, nullptr, dinv, A, n, 64, 64, 0);
    k_agg<64, 0><<<ga, 256, 0, stream>>>(A, rowptr, colA, dinv, b2, B, n);
    // conv3 (relu, output pre-scaled by dinv for SG chain)
    k_mm<64, 64, true, false><<<gm64, 256, 0, stream>>>(B, w3, nullptr, dinv, A, n, 64, 64, 0);
    k_agg<64, 2><<<ga, 256, 0, stream>>>(A, rowptr, colA, dinv, b3, B, n);
    // SGConv K=4 propagates (scaled-domain chain, final unscales)
    k_agg<64, 3><<<ga, 256, 0, stream>>>(B, rowptr, colA, dinv, b3, A, n);
    k_agg<64, 3><<<ga, 256, 0, stream>>>(A, rowptr, colA, dinv, b3, B, n);
    k_agg<64, 3><<<ga, 256, 0, stream>>>(B, rowptr, colA, dinv, b3, A, n);
    k_agg<64, 4><<<ga, 256, 0, stream>>>(A, rowptr, colA, dinv, b3, B, n);
    // SG linear (+bias, no scale)
    k_mm<64, 64, false, true><<<gm64, 256, 0, stream>>>(B, sgw, sgb, dinv, A, n, 64, 64, 0);
    // global max pool + MLP heads
    k_pool<<<(n + 127) / 128, 64, 0, stream>>>(A, batch, pooled, n);
    k_mlp<<<1, 256, 0, stream>>>(pooled, fc1w, fc1b, fc2w, fc2b, cpdw, cpdb, combw, combb, outp, G);
}

// Round 2
// 1596.405 us; speedup vs baseline: 1.2263x; 1.2263x over previous
//
#include <hip/hip_runtime.h>
#include <cfloat>

#define DEV __device__ __forceinline__

DEV unsigned enc_ord(float f) {
    unsigned u = __float_as_uint(f);
    return (u & 0x80000000u) ? ~u : (u | 0x80000000u);
}

// ================= bucketed CSR build =================
// Buckets of 512 dst nodes: bucket = dst >> 9. nb = ceil(n/512) (196 for n=100000).

// count edges per bucket (LDS histogram, one global atomic per bucket per block)
__global__ __launch_bounds__(256) void k_bcount(const int* __restrict__ dst, int* __restrict__ bcnt, int E) {
    __shared__ int hist[256];
    int tid = threadIdx.x;
    hist[tid] = 0;
    __syncthreads();
    int base = blockIdx.x * 4096;
#pragma unroll
    for (int j = 0; j < 16; ++j) {
        int e = base + j * 256 + tid;
        if (e < E) atomicAdd(&hist[dst[e] >> 9], 1);
    }
    __syncthreads();
    if (hist[tid]) atomicAdd(&bcnt[tid], hist[tid]);
}

// scan bucket counts -> bucketBase, init bucketCursor, set rowptr[n]=E
__global__ __launch_bounds__(256) void k_bscan(const int* __restrict__ bcnt, int* __restrict__ bbase,
                                               int* __restrict__ bcur, int* __restrict__ rowptr,
                                               int nb, int n, int E) {
    __shared__ int sh[256];
    int tid = threadIdx.x;
    int v = (tid < nb) ? bcnt[tid] : 0;
    sh[tid] = v; __syncthreads();
    for (int off = 1; off < 256; off <<= 1) {
        int x = (tid >= off) ? sh[tid - off] : 0; __syncthreads();
        sh[tid] += x; __syncthreads();
    }
    int excl = sh[tid] - v;
    if (tid < nb) { bbase[tid] = excl; bcur[tid] = excl; }
    if (tid == 0) { bbase[nb] = E; rowptr[n] = E; }
}

// scatter (src,dst) pairs into bucket-partitioned order
__global__ __launch_bounds__(256) void k_bscatter(const int* __restrict__ ei, int* __restrict__ bcur,
                                                  int2* __restrict__ pairs, int E) {
    __shared__ int hist[256];
    __shared__ int gbase[256];
    int tid = threadIdx.x;
    hist[tid] = 0;
    __syncthreads();
    int base = blockIdx.x * 4096;
    int d[16], li[16];
#pragma unroll
    for (int j = 0; j < 16; ++j) {
        int e = base + j * 256 + tid;
        if (e < E) {
            d[j] = ei[E + e];
            li[j] = atomicAdd(&hist[d[j] >> 9], 1);
        }
    }
    __syncthreads();
    if (hist[tid]) gbase[tid] = atomicAdd(&bcur[tid], hist[tid]);
    __syncthreads();
#pragma unroll
    for (int j = 0; j < 16; ++j) {
        int e = base + j * 256 + tid;
        if (e < E) {
            int b = d[j] >> 9;
            pairs[gbase[b] + li[j]] = make_int2(ei[e], d[j]);
        }
    }
}

// per-bucket: LDS deg histogram -> scan -> rowptr/dinv, then LDS-cursor fill of colA
__global__ __launch_bounds__(512) void k_bfill(const int2* __restrict__ pairs, const int* __restrict__ bbase,
                                               int* __restrict__ rowptr, float* __restrict__ dinv,
                                               int* __restrict__ colA, int n) {
    __shared__ int sdeg[512];
    __shared__ int scur[512];
    int tid = threadIdx.x;
    int b = blockIdx.x;
    int bb = bbase[b], be = bbase[b + 1];
    int nodeBase = b << 9;
    sdeg[tid] = 0;
    __syncthreads();
    for (int e = bb + tid; e < be; e += 512) {
        int2 pr = pairs[e];
        atomicAdd(&sdeg[pr.y & 511], 1);
    }
    __syncthreads();
    int v = sdeg[tid];
    __syncthreads();
    // inclusive scan over 512
    sdeg[tid] = v; __syncthreads();
    for (int off = 1; off < 512; off <<= 1) {
        int x = (tid >= off) ? sdeg[tid - off] : 0; __syncthreads();
        sdeg[tid] += x; __syncthreads();
    }
    int excl = sdeg[tid] - v;
    scur[tid] = excl;
    int node = nodeBase + tid;
    if (node < n) {
        rowptr[node] = bb + excl;
        dinv[node] = rsqrtf((float)v + 1.0f);  // +1 self loop
    }
    __syncthreads();
    for (int e = bb + tid; e < be; e += 512) {
        int2 pr = pairs[e];
        int p = atomicAdd(&scur[pr.y & 511], 1);
        colA[bb + p] = pr.x;
    }
}

// ================= dense matmul =================
// out[r,c] = (dinv[r]?) * sum_k in[r,k]*W[k,c] (+bias)
template <int K, int COUT, bool SCALE, bool BIAS>
__global__ __launch_bounds__(256) void k_mm(const float* __restrict__ in, const float* __restrict__ W,
                                            const float* __restrict__ bias, const float* __restrict__ dinv,
                                            float* __restrict__ out, int n, int ldw, int ldo, int colOff) {
    constexpr int CG = COUT / 4;
    constexpr int SLOTS = 256 / CG;
    constexpr int TR = (K == 128) ? 32 : 64;
    constexpr int RPT = TR / SLOTS;
    constexpr int KP = K + 1;
    __shared__ __align__(16) float sW[K * COUT];
    __shared__ float sH[TR * KP];
    const int tid = threadIdx.x;
    const int rowBase = blockIdx.x * TR;

    constexpr int W4 = COUT / 4;
    for (int idx = tid; idx < K * W4; idx += 256) {
        int k = idx / W4, c4 = idx - k * W4;
        ((float4*)sW)[idx] = *(const float4*)(W + (size_t)k * ldw + colOff + c4 * 4);
    }
    const float4* inp4 = (const float4*)(in + (size_t)rowBase * K);
    for (int idx = tid; idx < TR * K / 4; idx += 256) {
        int elem = idx * 4;
        int r = elem / K, k = elem - r * K;
        float4 h = (rowBase + r < n) ? inp4[idx] : make_float4(0.f, 0.f, 0.f, 0.f);
        float* dd = &sH[r * KP + k];
        dd[0] = h.x; dd[1] = h.y; dd[2] = h.z; dd[3] = h.w;
    }
    __syncthreads();

    const int cg = tid % CG;
    const int slot = tid / CG;
    float4 acc[RPT];
#pragma unroll
    for (int j = 0; j < RPT; ++j) acc[j] = make_float4(0.f, 0.f, 0.f, 0.f);
#pragma unroll 4
    for (int k = 0; k < K; ++k) {
        float4 w = *(const float4*)&sW[k * COUT + cg * 4];
#pragma unroll
        for (int j = 0; j < RPT; ++j) {
            float h = sH[(slot + j * SLOTS) * KP + k];
            acc[j].x += h * w.x; acc[j].y += h * w.y; acc[j].z += h * w.z; acc[j].w += h * w.w;
        }
    }
#pragma unroll
    for (int j = 0; j < RPT; ++j) {
        int r = rowBase + slot + j * SLOTS;
        if (r < n) {
            float4 o = acc[j];
            if (SCALE) { float di = dinv[r]; o.x *= di; o.y *= di; o.z *= di; o.w *= di; }
            if (BIAS) {
                float4 b = *(const float4*)(bias + colOff + cg * 4);
                o.x += b.x; o.y += b.y; o.z += b.z; o.w += b.w;
            }
            *(float4*)(out + (size_t)r * ldo + colOff + cg * 4) = o;
        }
    }
}

// ================= aggregation (pull, float4 lanes) =================
// s_i = g[i] + sum_{e in in(i)} g[col[e]]
// MODE 0: out = relu(dinv*s + b)       MODE 1: out = dinv*s + b
// MODE 2: out = dinv*relu(dinv*s + b)  MODE 3: out = dinv^2*s   MODE 4: out = dinv*s
template <int WIDTH, int MODE>
__global__ __launch_bounds__(256) void k_agg(const float* __restrict__ g, const int* __restrict__ rowptr,
                                             const int* __restrict__ col, const float* __restrict__ dinv,
                                             const float* __restrict__ bias, float* __restrict__ out, int n) {
    constexpr int LPR = WIDTH / 4;   // lanes per row (16 or 32)
    constexpr int RPW = 64 / LPR;    // rows per wave (4 or 2)
    int gw = (blockIdx.x * 256 + threadIdx.x) >> 6;
    int lane = threadIdx.x & 63;
    int seg = lane / LPR;
    int sl = lane % LPR;
    int row = gw * RPW + seg;
    if (row >= n) return;
    const int co = sl * 4;
    float4 acc = *(const float4*)(g + (size_t)row * WIDTH + co);  // self loop
    int e = rowptr[row], e1 = rowptr[row + 1];
    for (; e + 4 <= e1; e += 4) {
        int c0 = col[e], c1 = col[e + 1], c2 = col[e + 2], c3 = col[e + 3];
        float4 v0 = *(const float4*)(g + (size_t)c0 * WIDTH + co);
        float4 v1 = *(const float4*)(g + (size_t)c1 * WIDTH + co);
        float4 v2 = *(const float4*)(g + (size_t)c2 * WIDTH + co);
        float4 v3 = *(const float4*)(g + (size_t)c3 * WIDTH + co);
        acc.x += (v0.x + v1.x) + (v2.x + v3.x);
        acc.y += (v0.y + v1.y) + (v2.y + v3.y);
        acc.z += (v0.z + v1.z) + (v2.z + v3.z);
        acc.w += (v0.w + v1.w) + (v2.w + v3.w);
    }
    for (; e < e1; ++e) {
        float4 v = *(const float4*)(g + (size_t)col[e] * WIDTH + co);
        acc.x += v.x; acc.y += v.y; acc.z += v.z; acc.w += v.w;
    }
    float di = dinv[row];
    float4 o;
    if (MODE == 0) {
        float4 b = *(const float4*)(bias + co);
        o.x = fmaxf(di * acc.x + b.x, 0.f); o.y = fmaxf(di * acc.y + b.y, 0.f);
        o.z = fmaxf(di * acc.z + b.z, 0.f); o.w = fmaxf(di * acc.w + b.w, 0.f);
    } else if (MODE == 1) {
        float4 b = *(const float4*)(bias + co);
        o.x = di * acc.x + b.x; o.y = di * acc.y + b.y;
        o.z = di * acc.z + b.z; o.w = di * acc.w + b.w;
    } else if (MODE == 2) {
        float4 b = *(const float4*)(bias + co);
        o.x = di * fmaxf(di * acc.x + b.x, 0.f); o.y = di * fmaxf(di * acc.y + b.y, 0.f);
        o.z = di * fmaxf(di * acc.z + b.z, 0.f); o.w = di * fmaxf(di * acc.w + b.w, 0.f);
    } else if (MODE == 3) {
        float d2 = di * di;
        o.x = acc.x * d2; o.y = acc.y * d2; o.z = acc.z * d2; o.w = acc.w * d2;
    } else {
        o.x = acc.x * di; o.y = acc.y * di; o.z = acc.z * di; o.w = acc.w * di;
    }
    *(float4*)(out + (size_t)row * WIDTH + co) = o;
}

// ================= global max pool (batch sorted) =================
__global__ __launch_bounds__(64) void k_pool(const float* __restrict__ z, const int* __restrict__ batch,
                                             unsigned* __restrict__ pooled, int n) {
    constexpr int ROWS = 128;
    int lane = threadIdx.x;
    int r0 = blockIdx.x * ROWS;
    if (r0 >= n) return;
    int r1 = min(r0 + ROWS, n);
    int cur = batch[r0];
    float m = -FLT_MAX;
    for (int r = r0; r < r1; ++r) {
        int b = batch[r];
        float v = z[(size_t)r * 64 + lane];
        if (b != cur) {
            atomicMax(&pooled[cur * 64 + lane], enc_ord(m));
            cur = b; m = v;
        } else {
            m = fmaxf(m, v);
        }
    }
    atomicMax(&pooled[cur * 64 + lane], enc_ord(m));
}

// ================= final MLP =================
__global__ __launch_bounds__(256) void k_mlp(const unsigned* __restrict__ pooled,
                                             const float* __restrict__ fc1w, const float* __restrict__ fc1b,
                                             const float* __restrict__ fc2w, const float* __restrict__ fc2b,
                                             const float* __restrict__ cpdw, const float* __restrict__ cpdb,
                                             const float* __restrict__ combw, const float* __restrict__ combb,
                                             float* __restrict__ out, int G) {
    __shared__ float s1[64 * 32], s2[32 * 16], sb1[32], sb2[16], scw[16], sow[16], shead[2];
    int tid = threadIdx.x;
    for (int i = tid; i < 2048; i += 256) s1[i] = fc1w[i];
    for (int i = tid; i < 512; i += 256) s2[i] = fc2w[i];
    if (tid < 32) sb1[tid] = fc1b[tid];
    if (tid < 16) { sb2[tid] = fc2b[tid]; scw[tid] = cpdw[tid]; sow[tid] = combw[tid]; }
    if (tid == 0) { shead[0] = cpdb[0]; shead[1] = combb[0]; }
    __syncthreads();
    if (tid < G) {
        float h0[64];
#pragma unroll
        for (int k = 0; k < 64; ++k) {
            unsigned u = pooled[tid * 64 + k];
            unsigned b = (u & 0x80000000u) ? (u & 0x7fffffffu) : ~u;
            h0[k] = __uint_as_float(b);
        }
        float h1[32];
#pragma unroll
        for (int j = 0; j < 32; ++j) {
            float a = sb1[j];
#pragma unroll
            for (int k = 0; k < 64; ++k) a += h0[k] * s1[k * 32 + j];
            h1[j] = fmaxf(a, 0.f);
        }
        float h2[16];
#pragma unroll
        for (int j = 0; j < 16; ++j) {
            float a = sb2[j];
#pragma unroll
            for (int k = 0; k < 32; ++k) a += h1[k] * s2[k * 16 + j];
            h2[j] = fmaxf(a, 0.f);
        }
        float c1 = shead[0], c2 = shead[1];
#pragma unroll
        for (int k = 0; k < 16; ++k) { c1 += h2[k] * scw[k]; c2 += h2[k] * sow[k]; }
        out[tid] = c1;
        out[G + tid] = c2;
    }
}

extern "C" void kernel_launch(void* const* d_in, const int* in_sizes, int n_in,
                              void* d_out, int out_size, void* d_ws, size_t ws_size,
                              hipStream_t stream) {
    const float* x      = (const float*)d_in[0];
    const int*   ei     = (const int*)d_in[1];
    const int*   batch  = (const int*)d_in[2];
    const float* enc_w1 = (const float*)d_in[3];
    const float* enc_b1 = (const float*)d_in[4];
    const float* enc_w2 = (const float*)d_in[5];
    const float* enc_b2 = (const float*)d_in[6];
    const float* w1 = (const float*)d_in[7];   const float* b1 = (const float*)d_in[8];
    const float* w2 = (const float*)d_in[9];   const float* b2 = (const float*)d_in[10];
    const float* w3 = (const float*)d_in[11];  const float* b3 = (const float*)d_in[12];
    const float* sgw = (const float*)d_in[13]; const float* sgb = (const float*)d_in[14];
    const float* fc1w = (const float*)d_in[15]; const float* fc1b = (const float*)d_in[16];
    const float* fc2w = (const float*)d_in[17]; const float* fc2b = (const float*)d_in[18];
    const float* cpdw = (const float*)d_in[19]; const float* cpdb = (const float*)d_in[20];
    const float* combw = (const float*)d_in[21]; const float* combb = (const float*)d_in[22];

    const int n = in_sizes[0] / 128;
    const int E = in_sizes[1] / 2;
    const int G = out_size / 2;
    const int nb = (n + 511) >> 9;  // buckets of 512 dst nodes
    float* outp = (float*)d_out;

    char* p = (char*)d_ws;
    auto alloc = [&](size_t bytes) -> char* {
        char* r = p;
        p += (bytes + 255) & ~(size_t)255;
        return r;
    };
    int* rowptr      = (int*)alloc((size_t)(n + 1) * 4);
    float* dinv      = (float*)alloc((size_t)n * 4);
    int* bcnt        = (int*)alloc(256 * 4);
    int* bbase       = (int*)alloc(257 * 4);
    int* bcur        = (int*)alloc(256 * 4);
    int* colA        = (int*)alloc((size_t)E * 4);
    unsigned* pooled = (unsigned*)alloc((size_t)G * 64 * 4);
    float* A         = (float*)alloc((size_t)n * 128 * 4);
    float* B         = (float*)alloc((size_t)n * 128 * 4);
    int2* pairs      = (int2*)A;  // alias: pairs dead before first k_mm writes A

    hipMemsetAsync(bcnt, 0, 256 * 4, stream);
    hipMemsetAsync(pooled, 0, (size_t)G * 64 * 4, stream);

    const int gE = (E + 4095) / 4096;
    k_bcount<<<gE, 256, 0, stream>>>(ei + E, bcnt, E);
    k_bscan<<<1, 256, 0, stream>>>(bcnt, bbase, bcur, rowptr, nb, n, E);
    k_bscatter<<<gE, 256, 0, stream>>>(ei, bcur, pairs, E);
    k_bfill<<<nb, 512, 0, stream>>>(pairs, bbase, rowptr, dinv, colA, n);

    const int gm128 = (n + 31) / 32;
    const int gm64  = (n + 63) / 64;
    const int ga64  = (n + 15) / 16;   // 4 rows/wave, 4 waves/block
    const int ga128 = (n + 7) / 8;     // 2 rows/wave

    // encoder layer 1
    k_mm<128, 64, true, false><<<gm128, 256, 0, stream>>>(x, enc_w1, nullptr, dinv, A, n, 128, 128, 0);
    k_mm<128, 64, true, false><<<gm128, 256, 0, stream>>>(x, enc_w1, nullptr, dinv, A, n, 128, 128, 64);
    k_agg<128, 0><<<ga128, 256, 0, stream>>>(A, rowptr, colA, dinv, enc_b1, B, n);
    // encoder layer 2
    k_mm<128, 64, true, false><<<gm128, 256, 0, stream>>>(B, enc_w2, nullptr, dinv, A, n, 64, 64, 0);
    k_agg<64, 1><<<ga64, 256, 0, stream>>>(A, rowptr, colA, dinv, enc_b2, B, n);
    // conv1, conv2
    k_mm<64, 64, true, false><<<gm64, 256, 0, stream>>>(B, w1, nullptr, dinv, A, n, 64, 64, 0);
    k_agg<64, 0><<<ga64, 256, 0, stream>>>(A, rowptr, colA, dinv, b1, B, n);
    k_mm<64, 64, true, false><<<gm64, 256, 0, stream>>>(B, w2, nullptr, dinv, A, n, 64, 64, 0);
    k_agg<64, 0><<<ga64, 256, 0, stream>>>(A, rowptr, colA, dinv, b2, B, n);
    // conv3 (output pre-scaled by dinv for SG chain)
    k_mm<64, 64, true, false><<<gm64, 256, 0, stream>>>(B, w3, nullptr, dinv, A, n, 64, 64, 0);
    k_agg<64, 2><<<ga64, 256, 0, stream>>>(A, rowptr, colA, dinv, b3, B, n);
    // SGConv K=4 propagates
    k_agg<64, 3><<<ga64, 256, 0, stream>>>(B, rowptr, colA, dinv, b3, A, n);
    k_agg<64, 3><<<ga64, 256, 0, stream>>>(A, rowptr, colA, dinv, b3, B, n);
    k_agg<64, 3><<<ga64, 256, 0, stream>>>(B, rowptr, colA, dinv, b3, A, n);
    k_agg<64, 4><<<ga64, 256, 0, stream>>>(A, rowptr, colA, dinv, b3, B, n);
    // SG linear
    k_mm<64, 64, false, true><<<gm64, 256, 0, stream>>>(B, sgw, sgb, dinv, A, n, 64, 64, 0);
    // pool + heads
    k_pool<<<(n + 127) / 128, 64, 0, stream>>>(A, batch, pooled, n);
    k_mlp<<<1, 256, 0, stream>>>(pooled, fc1w, fc1b, fc2w, fc2b, cpdw, cpdb, combw, combb, outp, G);
}

// Round 3
// 1572.274 us; speedup vs baseline: 1.2451x; 1.0153x over previous
//
#include <hip/hip_runtime.h>
#include <cfloat>

#define DEV __device__ __forceinline__

DEV unsigned enc_ord(float f) {
    unsigned u = __float_as_uint(f);
    return (u & 0x80000000u) ? ~u : (u | 0x80000000u);
}

// ================= bucketed CSR build =================
// Buckets of 512 dst nodes: bucket = dst >> 9.

__global__ __launch_bounds__(256) void k_bcount(const int* __restrict__ dst, int* __restrict__ bcnt, int E) {
    __shared__ int hist[256];
    int tid = threadIdx.x;
    hist[tid] = 0;
    __syncthreads();
    int base = blockIdx.x * 4096;
#pragma unroll
    for (int j = 0; j < 16; ++j) {
        int e = base + j * 256 + tid;
        if (e < E) atomicAdd(&hist[dst[e] >> 9], 1);
    }
    __syncthreads();
    if (hist[tid]) atomicAdd(&bcnt[tid], hist[tid]);
}

__global__ __launch_bounds__(256) void k_bscan(const int* __restrict__ bcnt, int* __restrict__ bbase,
                                               int* __restrict__ bcur, int* __restrict__ rowptr,
                                               int nb, int n, int E) {
    __shared__ int sh[256];
    int tid = threadIdx.x;
    int v = (tid < nb) ? bcnt[tid] : 0;
    sh[tid] = v; __syncthreads();
    for (int off = 1; off < 256; off <<= 1) {
        int x = (tid >= off) ? sh[tid - off] : 0; __syncthreads();
        sh[tid] += x; __syncthreads();
    }
    int excl = sh[tid] - v;
    if (tid < nb) { bbase[tid] = excl; bcur[tid] = excl; }
    if (tid == 0) { bbase[nb] = E; rowptr[n] = E; }
}

__global__ __launch_bounds__(256) void k_bscatter(const int* __restrict__ ei, int* __restrict__ bcur,
                                                  int2* __restrict__ pairs, int E) {
    __shared__ int hist[256];
    __shared__ int gbase[256];
    int tid = threadIdx.x;
    hist[tid] = 0;
    __syncthreads();
    int base = blockIdx.x * 4096;
    int d[16], li[16];
#pragma unroll
    for (int j = 0; j < 16; ++j) {
        int e = base + j * 256 + tid;
        if (e < E) {
            d[j] = ei[E + e];
            li[j] = atomicAdd(&hist[d[j] >> 9], 1);
        }
    }
    __syncthreads();
    if (hist[tid]) gbase[tid] = atomicAdd(&bcur[tid], hist[tid]);
    __syncthreads();
#pragma unroll
    for (int j = 0; j < 16; ++j) {
        int e = base + j * 256 + tid;
        if (e < E) {
            int b = d[j] >> 9;
            pairs[gbase[b] + li[j]] = make_int2(ei[e], d[j]);
        }
    }
}

__global__ __launch_bounds__(512) void k_bfill(const int2* __restrict__ pairs, const int* __restrict__ bbase,
                                               int* __restrict__ rowptr, float* __restrict__ dinv,
                                               int* __restrict__ colA, int n) {
    __shared__ int sdeg[512];
    __shared__ int scur[512];
    int tid = threadIdx.x;
    int b = blockIdx.x;
    int bb = bbase[b], be = bbase[b + 1];
    int nodeBase = b << 9;
    sdeg[tid] = 0;
    __syncthreads();
    for (int e = bb + tid; e < be; e += 512) {
        int2 pr = pairs[e];
        atomicAdd(&sdeg[pr.y & 511], 1);
    }
    __syncthreads();
    int v = sdeg[tid];
    __syncthreads();
    sdeg[tid] = v; __syncthreads();
    for (int off = 1; off < 512; off <<= 1) {
        int x = (tid >= off) ? sdeg[tid - off] : 0; __syncthreads();
        sdeg[tid] += x; __syncthreads();
    }
    int excl = sdeg[tid] - v;
    scur[tid] = excl;
    int node = nodeBase + tid;
    if (node < n) {
        rowptr[node] = bb + excl;
        dinv[node] = rsqrtf((float)v + 1.0f);  // +1 self loop
    }
    __syncthreads();
    for (int e = bb + tid; e < be; e += 512) {
        int2 pr = pairs[e];
        int p = atomicAdd(&scur[pr.y & 511], 1);
        colA[bb + p] = pr.x;
    }
}

// ================= dense matmul =================
template <int K, int COUT, bool SCALE, bool BIAS>
__global__ __launch_bounds__(256) void k_mm(const float* __restrict__ in, const float* __restrict__ W,
                                            const float* __restrict__ bias, const float* __restrict__ dinv,
                                            float* __restrict__ out, int n, int ldw, int ldo, int colOff) {
    constexpr int CG = COUT / 4;
    constexpr int SLOTS = 256 / CG;
    constexpr int TR = (K == 128) ? 32 : 64;
    constexpr int RPT = TR / SLOTS;
    constexpr int KP = K + 1;
    __shared__ __align__(16) float sW[K * COUT];
    __shared__ float sH[TR * KP];
    const int tid = threadIdx.x;
    const int rowBase = blockIdx.x * TR;

    constexpr int W4 = COUT / 4;
    for (int idx = tid; idx < K * W4; idx += 256) {
        int k = idx / W4, c4 = idx - k * W4;
        ((float4*)sW)[idx] = *(const float4*)(W + (size_t)k * ldw + colOff + c4 * 4);
    }
    const float4* inp4 = (const float4*)(in + (size_t)rowBase * K);
    for (int idx = tid; idx < TR * K / 4; idx += 256) {
        int elem = idx * 4;
        int r = elem / K, k = elem - r * K;
        float4 h = (rowBase + r < n) ? inp4[idx] : make_float4(0.f, 0.f, 0.f, 0.f);
        float* dd = &sH[r * KP + k];
        dd[0] = h.x; dd[1] = h.y; dd[2] = h.z; dd[3] = h.w;
    }
    __syncthreads();

    const int cg = tid % CG;
    const int slot = tid / CG;
    float4 acc[RPT];
#pragma unroll
    for (int j = 0; j < RPT; ++j) acc[j] = make_float4(0.f, 0.f, 0.f, 0.f);
#pragma unroll 4
    for (int k = 0; k < K; ++k) {
        float4 w = *(const float4*)&sW[k * COUT + cg * 4];
#pragma unroll
        for (int j = 0; j < RPT; ++j) {
            float h = sH[(slot + j * SLOTS) * KP + k];
            acc[j].x += h * w.x; acc[j].y += h * w.y; acc[j].z += h * w.z; acc[j].w += h * w.w;
        }
    }
#pragma unroll
    for (int j = 0; j < RPT; ++j) {
        int r = rowBase + slot + j * SLOTS;
        if (r < n) {
            float4 o = acc[j];
            if (SCALE) { float di = dinv[r]; o.x *= di; o.y *= di; o.z *= di; o.w *= di; }
            if (BIAS) {
                float4 b = *(const float4*)(bias + colOff + cg * 4);
                o.x += b.x; o.y += b.y; o.z += b.z; o.w += b.w;
            }
            *(float4*)(out + (size_t)r * ldo + colOff + cg * 4) = o;
        }
    }
}

// ================= aggregation (pull, 8-deep pipelined gathers) =================
// s_i = g[i] + sum_{e in in(i)} g[col[e]]
// MODE 0: out = relu(dinv*s + b)       MODE 1: out = dinv*s + b
// MODE 2: out = dinv*relu(dinv*s + b)  MODE 3: out = dinv^2*s   MODE 4: out = dinv*s
template <int WIDTH, int MODE>
__global__ __launch_bounds__(256) void k_agg(const float* __restrict__ g, const int* __restrict__ rowptr,
                                             const int* __restrict__ col, const float* __restrict__ dinv,
                                             const float* __restrict__ bias, float* __restrict__ out, int n) {
    constexpr int LPR = WIDTH / 4;   // lanes per row (16 or 32)
    constexpr int RPW = 64 / LPR;    // rows per wave (4 or 2)
    int gw = (blockIdx.x * 256 + threadIdx.x) >> 6;
    int lane = threadIdx.x & 63;
    int seg = lane / LPR;
    int sl = lane % LPR;
    int row = gw * RPW + seg;
    if (row >= n) return;
    const float4* g4 = (const float4*)g + sl;
    float4 acc = g4[(size_t)row * LPR];  // self loop
    int e0 = rowptr[row], e1 = rowptr[row + 1];
    if (e0 < e1) {
        const int e1m1 = e1 - 1;
        int c[8];
#pragma unroll
        for (int j = 0; j < 8; ++j) c[j] = col[min(e0 + j, e1m1)];
        for (int eb = e0; eb < e1; eb += 8) {
            // issue 8 gathers from the preloaded indices
            float4 v[8];
#pragma unroll
            for (int j = 0; j < 8; ++j) v[j] = g4[(size_t)c[j] * LPR];
            // prefetch next batch's col indices (independent of gathers)
            int cn[8];
#pragma unroll
            for (int j = 0; j < 8; ++j) cn[j] = col[min(eb + 8 + j, e1m1)];
            // masked accumulate (tail lanes gather a duplicate line -> no extra traffic)
            int rem = e1 - eb;
#pragma unroll
            for (int j = 0; j < 8; ++j) {
                float m = (j < rem) ? 1.f : 0.f;
                acc.x = fmaf(m, v[j].x, acc.x);
                acc.y = fmaf(m, v[j].y, acc.y);
                acc.z = fmaf(m, v[j].z, acc.z);
                acc.w = fmaf(m, v[j].w, acc.w);
            }
#pragma unroll
            for (int j = 0; j < 8; ++j) c[j] = cn[j];
        }
    }
    float di = dinv[row];
    float4 o;
    if (MODE == 0) {
        float4 b = *(const float4*)(bias + sl * 4);
        o.x = fmaxf(di * acc.x + b.x, 0.f); o.y = fmaxf(di * acc.y + b.y, 0.f);
        o.z = fmaxf(di * acc.z + b.z, 0.f); o.w = fmaxf(di * acc.w + b.w, 0.f);
    } else if (MODE == 1) {
        float4 b = *(const float4*)(bias + sl * 4);
        o.x = di * acc.x + b.x; o.y = di * acc.y + b.y;
        o.z = di * acc.z + b.z; o.w = di * acc.w + b.w;
    } else if (MODE == 2) {
        float4 b = *(const float4*)(bias + sl * 4);
        o.x = di * fmaxf(di * acc.x + b.x, 0.f); o.y = di * fmaxf(di * acc.y + b.y, 0.f);
        o.z = di * fmaxf(di * acc.z + b.z, 0.f); o.w = di * fmaxf(di * acc.w + b.w, 0.f);
    } else if (MODE == 3) {
        float d2 = di * di;
        o.x = acc.x * d2; o.y = acc.y * d2; o.z = acc.z * d2; o.w = acc.w * d2;
    } else {
        o.x = acc.x * di; o.y = acc.y * di; o.z = acc.z * di; o.w = acc.w * di;
    }
    *(float4*)(out + (size_t)row * WIDTH + sl * 4) = o;
}

// ================= global max pool (batch sorted) =================
__global__ __launch_bounds__(64) void k_pool(const float* __restrict__ z, const int* __restrict__ batch,
                                             unsigned* __restrict__ pooled, int n) {
    constexpr int ROWS = 128;
    int lane = threadIdx.x;
    int r0 = blockIdx.x * ROWS;
    if (r0 >= n) return;
    int r1 = min(r0 + ROWS, n);
    int cur = batch[r0];
    float m = -FLT_MAX;
    for (int r = r0; r < r1; ++r) {
        int b = batch[r];
        float v = z[(size_t)r * 64 + lane];
        if (b != cur) {
            atomicMax(&pooled[cur * 64 + lane], enc_ord(m));
            cur = b; m = v;
        } else {
            m = fmaxf(m, v);
        }
    }
    atomicMax(&pooled[cur * 64 + lane], enc_ord(m));
}

// ================= final MLP =================
__global__ __launch_bounds__(256) void k_mlp(const unsigned* __restrict__ pooled,
                                             const float* __restrict__ fc1w, const float* __restrict__ fc1b,
                                             const float* __restrict__ fc2w, const float* __restrict__ fc2b,
                                             const float* __restrict__ cpdw, const float* __restrict__ cpdb,
                                             const float* __restrict__ combw, const float* __restrict__ combb,
                                             float* __restrict__ out, int G) {
    __shared__ float s1[64 * 32], s2[32 * 16], sb1[32], sb2[16], scw[16], sow[16], shead[2];
    int tid = threadIdx.x;
    for (int i = tid; i < 2048; i += 256) s1[i] = fc1w[i];
    for (int i = tid; i < 512; i += 256) s2[i] = fc2w[i];
    if (tid < 32) sb1[tid] = fc1b[tid];
    if (tid < 16) { sb2[tid] = fc2b[tid]; scw[tid] = cpdw[tid]; sow[tid] = combw[tid]; }
    if (tid == 0) { shead[0] = cpdb[0]; shead[1] = combb[0]; }
    __syncthreads();
    if (tid < G) {
        float h0[64];
#pragma unroll
        for (int k = 0; k < 64; ++k) {
            unsigned u = pooled[tid * 64 + k];
            unsigned b = (u & 0x80000000u) ? (u & 0x7fffffffu) : ~u;
            h0[k] = __uint_as_float(b);
        }
        float h1[32];
#pragma unroll
        for (int j = 0; j < 32; ++j) {
            float a = sb1[j];
#pragma unroll
            for (int k = 0; k < 64; ++k) a += h0[k] * s1[k * 32 + j];
            h1[j] = fmaxf(a, 0.f);
        }
        float h2[16];
#pragma unroll
        for (int j = 0; j < 16; ++j) {
            float a = sb2[j];
#pragma unroll
            for (int k = 0; k < 32; ++k) a += h1[k] * s2[k * 16 + j];
            h2[j] = fmaxf(a, 0.f);
        }
        float c1 = shead[0], c2 = shead[1];
#pragma unroll
        for (int k = 0; k < 16; ++k) { c1 += h2[k] * scw[k]; c2 += h2[k] * sow[k]; }
        out[tid] = c1;
        out[G + tid] = c2;
    }
}

extern "C" void kernel_launch(void* const* d_in, const int* in_sizes, int n_in,
                              void* d_out, int out_size, void* d_ws, size_t ws_size,
                              hipStream_t stream) {
    const float* x      = (const float*)d_in[0];
    const int*   ei     = (const int*)d_in[1];
    const int*   batch  = (const int*)d_in[2];
    const float* enc_w1 = (const float*)d_in[3];
    const float* enc_b1 = (const float*)d_in[4];
    const float* enc_w2 = (const float*)d_in[5];
    const float* enc_b2 = (const float*)d_in[6];
    const float* w1 = (const float*)d_in[7];   const float* b1 = (const float*)d_in[8];
    const float* w2 = (const float*)d_in[9];   const float* b2 = (const float*)d_in[10];
    const float* w3 = (const float*)d_in[11];  const float* b3 = (const float*)d_in[12];
    const float* sgw = (const float*)d_in[13]; const float* sgb = (const float*)d_in[14];
    const float* fc1w = (const float*)d_in[15]; const float* fc1b = (const float*)d_in[16];
    const float* fc2w = (const float*)d_in[17]; const float* fc2b = (const float*)d_in[18];
    const float* cpdw = (const float*)d_in[19]; const float* cpdb = (const float*)d_in[20];
    const float* combw = (const float*)d_in[21]; const float* combb = (const float*)d_in[22];

    const int n = in_sizes[0] / 128;
    const int E = in_sizes[1] / 2;
    const int G = out_size / 2;
    const int nb = (n + 511) >> 9;
    float* outp = (float*)d_out;

    char* p = (char*)d_ws;
    auto alloc = [&](size_t bytes) -> char* {
        char* r = p;
        p += (bytes + 255) & ~(size_t)255;
        return r;
    };
    int* rowptr      = (int*)alloc((size_t)(n + 1) * 4);
    float* dinv      = (float*)alloc((size_t)n * 4);
    int* bcnt        = (int*)alloc(256 * 4);
    int* bbase       = (int*)alloc(257 * 4);
    int* bcur        = (int*)alloc(256 * 4);
    int* colA        = (int*)alloc((size_t)E * 4);
    unsigned* pooled = (unsigned*)alloc((size_t)G * 64 * 4);
    float* A         = (float*)alloc((size_t)n * 128 * 4);
    float* B         = (float*)alloc((size_t)n * 128 * 4);
    int2* pairs      = (int2*)A;  // alias: pairs dead before first k_mm writes A

    hipMemsetAsync(bcnt, 0, 256 * 4, stream);
    hipMemsetAsync(pooled, 0, (size_t)G * 64 * 4, stream);

    const int gE = (E + 4095) / 4096;
    k_bcount<<<gE, 256, 0, stream>>>(ei + E, bcnt, E);
    k_bscan<<<1, 256, 0, stream>>>(bcnt, bbase, bcur, rowptr, nb, n, E);
    k_bscatter<<<gE, 256, 0, stream>>>(ei, bcur, pairs, E);
    k_bfill<<<nb, 512, 0, stream>>>(pairs, bbase, rowptr, dinv, colA, n);

    const int gm128 = (n + 31) / 32;
    const int gm64  = (n + 63) / 64;
    const int ga64  = (n + 15) / 16;
    const int ga128 = (n + 7) / 8;

    // encoder layer 1
    k_mm<128, 64, true, false><<<gm128, 256, 0, stream>>>(x, enc_w1, nullptr, dinv, A, n, 128, 128, 0);
    k_mm<128, 64, true, false><<<gm128, 256, 0, stream>>>(x, enc_w1, nullptr, dinv, A, n, 128, 128, 64);
    k_agg<128, 0><<<ga128, 256, 0, stream>>>(A, rowptr, colA, dinv, enc_b1, B, n);
    // encoder layer 2
    k_mm<128, 64, true, false><<<gm128, 256, 0, stream>>>(B, enc_w2, nullptr, dinv, A, n, 64, 64, 0);
    k_agg<64, 1><<<ga64, 256, 0, stream>>>(A, rowptr, colA, dinv, enc_b2, B, n);
    // conv1, conv2
    k_mm<64, 64, true, false><<<gm64, 256, 0, stream>>>(B, w1, nullptr, dinv, A, n, 64, 64, 0);
    k_agg<64, 0><<<ga64, 256, 0, stream>>>(A, rowptr, colA, dinv, b1, B, n);
    k_mm<64, 64, true, false><<<gm64, 256, 0, stream>>>(B, w2, nullptr, dinv, A, n, 64, 64, 0);
    k_agg<64, 0><<<ga64, 256, 0, stream>>>(A, rowptr, colA, dinv, b2, B, n);
    // conv3 (output pre-scaled by dinv for SG chain)
    k_mm<64, 64, true, false><<<gm64, 256, 0, stream>>>(B, w3, nullptr, dinv, A, n, 64, 64, 0);
    k_agg<64, 2><<<ga64, 256, 0, stream>>>(A, rowptr, colA, dinv, b3, B, n);
    // SGConv K=4 propagates
    k_agg<64, 3><<<ga64, 256, 0, stream>>>(B, rowptr, colA, dinv, b3, A, n);
    k_agg<64, 3><<<ga64, 256, 0, stream>>>(A, rowptr, colA, dinv, b3, B, n);
    k_agg<64, 3><<<ga64, 256, 0, stream>>>(B, rowptr, colA, dinv, b3, A, n);
    k_agg<64, 4><<<ga64, 256, 0, stream>>>(A, rowptr, colA, dinv, b3, B, n);
    // SG linear
    k_mm<64, 64, false, true><<<gm64, 256, 0, stream>>>(B, sgw, sgb, dinv, A, n, 64, 64, 0);
    // pool + heads
    k_pool<<<(n + 127) / 128, 64, 0, stream>>>(A, batch, pooled, n);
    k_mlp<<<1, 256, 0, stream>>>(pooled, fc1w, fc1b, fc2w, fc2b, cpdw, cpdb, combw, combb, outp, G);
}

// Round 4
// 1008.293 us; speedup vs baseline: 1.9415x; 1.5593x over previous
//
#include <hip/hip_runtime.h>
#include <hip/hip_fp16.h>
#include <cfloat>
#include <type_traits>

#define DEV __device__ __forceinline__

DEV unsigned enc_ord(float f) {
    unsigned u = __float_as_uint(f);
    return (u & 0x80000000u) ? ~u : (u | 0x80000000u);
}

// ================= bucketed CSR build =================
__global__ __launch_bounds__(256) void k_bcount(const int* __restrict__ dst, int* __restrict__ bcnt, int E) {
    __shared__ int hist[256];
    int tid = threadIdx.x;
    hist[tid] = 0;
    __syncthreads();
    int base = blockIdx.x * 4096;
#pragma unroll
    for (int j = 0; j < 16; ++j) {
        int e = base + j * 256 + tid;
        if (e < E) atomicAdd(&hist[dst[e] >> 9], 1);
    }
    __syncthreads();
    if (hist[tid]) atomicAdd(&bcnt[tid], hist[tid]);
}

__global__ __launch_bounds__(256) void k_bscan(const int* __restrict__ bcnt, int* __restrict__ bbase,
                                               int* __restrict__ bcur, int* __restrict__ rowptr,
                                               int nb, int n, int E) {
    __shared__ int sh[256];
    int tid = threadIdx.x;
    int v = (tid < nb) ? bcnt[tid] : 0;
    sh[tid] = v; __syncthreads();
    for (int off = 1; off < 256; off <<= 1) {
        int x = (tid >= off) ? sh[tid - off] : 0; __syncthreads();
        sh[tid] += x; __syncthreads();
    }
    int excl = sh[tid] - v;
    if (tid < nb) { bbase[tid] = excl; bcur[tid] = excl; }
    if (tid == 0) { bbase[nb] = E; rowptr[n] = E; }
}

__global__ __launch_bounds__(256) void k_bscatter(const int* __restrict__ ei, int* __restrict__ bcur,
                                                  int2* __restrict__ pairs, int E) {
    __shared__ int hist[256];
    __shared__ int gbase[256];
    int tid = threadIdx.x;
    hist[tid] = 0;
    __syncthreads();
    int base = blockIdx.x * 4096;
    int d[16], li[16];
#pragma unroll
    for (int j = 0; j < 16; ++j) {
        int e = base + j * 256 + tid;
        if (e < E) {
            d[j] = ei[E + e];
            li[j] = atomicAdd(&hist[d[j] >> 9], 1);
        }
    }
    __syncthreads();
    if (hist[tid]) gbase[tid] = atomicAdd(&bcur[tid], hist[tid]);
    __syncthreads();
#pragma unroll
    for (int j = 0; j < 16; ++j) {
        int e = base + j * 256 + tid;
        if (e < E) {
            int b = d[j] >> 9;
            pairs[gbase[b] + li[j]] = make_int2(ei[e], d[j]);
        }
    }
}

__global__ __launch_bounds__(512) void k_bfill(const int2* __restrict__ pairs, const int* __restrict__ bbase,
                                               int* __restrict__ rowptr, float* __restrict__ dinv,
                                               int* __restrict__ colA, int n) {
    __shared__ int sdeg[512];
    __shared__ int scur[512];
    int tid = threadIdx.x;
    int b = blockIdx.x;
    int bb = bbase[b], be = bbase[b + 1];
    int nodeBase = b << 9;
    sdeg[tid] = 0;
    __syncthreads();
    for (int e = bb + tid; e < be; e += 512) {
        int2 pr = pairs[e];
        atomicAdd(&sdeg[pr.y & 511], 1);
    }
    __syncthreads();
    int v = sdeg[tid];
    __syncthreads();
    sdeg[tid] = v; __syncthreads();
    for (int off = 1; off < 512; off <<= 1) {
        int x = (tid >= off) ? sdeg[tid - off] : 0; __syncthreads();
        sdeg[tid] += x; __syncthreads();
    }
    int excl = sdeg[tid] - v;
    scur[tid] = excl;
    int node = nodeBase + tid;
    if (node < n) {
        rowptr[node] = bb + excl;
        dinv[node] = rsqrtf((float)v + 1.0f);  // +1 self loop
    }
    __syncthreads();
    for (int e = bb + tid; e < be; e += 512) {
        int2 pr = pairs[e];
        int p = atomicAdd(&scur[pr.y & 511], 1);
        colA[bb + p] = pr.x;
    }
}

// ================= dense matmul =================
// out[r,c] = (dinv[r]?) * sum_k in[r,k]*W[k,c] (+bias); fp32 compute, TIN/TOUT storage
template <int K, int COUT, bool SCALE, bool BIAS, typename TIN, typename TOUT>
__global__ __launch_bounds__(256) void k_mm(const TIN* __restrict__ in, const float* __restrict__ W,
                                            const float* __restrict__ bias, const float* __restrict__ dinv,
                                            TOUT* __restrict__ out, int n, int ldw, int ldo, int colOff) {
    constexpr int CG = COUT / 4;
    constexpr int SLOTS = 256 / CG;
    constexpr int TR = (K == 128) ? 32 : 64;
    constexpr int RPT = TR / SLOTS;
    constexpr int KP = K + 1;
    __shared__ __align__(16) float sW[K * COUT];
    __shared__ float sH[TR * KP];
    const int tid = threadIdx.x;
    const int rowBase = blockIdx.x * TR;

    constexpr int W4 = COUT / 4;
    for (int idx = tid; idx < K * W4; idx += 256) {
        int k = idx / W4, c4 = idx - k * W4;
        ((float4*)sW)[idx] = *(const float4*)(W + (size_t)k * ldw + colOff + c4 * 4);
    }
    if constexpr (std::is_same<TIN, float>::value) {
        const float4* inp4 = (const float4*)(in + (size_t)rowBase * K);
        for (int idx = tid; idx < TR * K / 4; idx += 256) {
            int elem = idx * 4;
            int r = elem / K, k = elem - r * K;
            float4 h = (rowBase + r < n) ? inp4[idx] : make_float4(0.f, 0.f, 0.f, 0.f);
            float* dd = &sH[r * KP + k];
            dd[0] = h.x; dd[1] = h.y; dd[2] = h.z; dd[3] = h.w;
        }
    } else {
        const uint4* inp8 = (const uint4*)(in + (size_t)rowBase * K);
        for (int idx = tid; idx < TR * K / 8; idx += 256) {
            int elem = idx * 8;
            int r = elem / K, k = elem - r * K;
            uint4 h = make_uint4(0u, 0u, 0u, 0u);
            if (rowBase + r < n) h = inp8[idx];
            const __half2* hh = (const __half2*)&h;
            float* dd = &sH[r * KP + k];
#pragma unroll
            for (int q = 0; q < 4; ++q) {
                float2 f = __half22float2(hh[q]);
                dd[2 * q] = f.x; dd[2 * q + 1] = f.y;
            }
        }
    }
    __syncthreads();

    const int cg = tid % CG;
    const int slot = tid / CG;
    float4 acc[RPT];
#pragma unroll
    for (int j = 0; j < RPT; ++j) acc[j] = make_float4(0.f, 0.f, 0.f, 0.f);
#pragma unroll 4
    for (int k = 0; k < K; ++k) {
        float4 w = *(const float4*)&sW[k * COUT + cg * 4];
#pragma unroll
        for (int j = 0; j < RPT; ++j) {
            float h = sH[(slot + j * SLOTS) * KP + k];
            acc[j].x += h * w.x; acc[j].y += h * w.y; acc[j].z += h * w.z; acc[j].w += h * w.w;
        }
    }
#pragma unroll
    for (int j = 0; j < RPT; ++j) {
        int r = rowBase + slot + j * SLOTS;
        if (r < n) {
            float4 o = acc[j];
            if (SCALE) { float di = dinv[r]; o.x *= di; o.y *= di; o.z *= di; o.w *= di; }
            if (BIAS) {
                float4 b = *(const float4*)(bias + colOff + cg * 4);
                o.x += b.x; o.y += b.y; o.z += b.z; o.w += b.w;
            }
            if constexpr (std::is_same<TOUT, float>::value) {
                *(float4*)(out + (size_t)r * ldo + colOff + cg * 4) = o;
            } else {
                __half2 p0 = __floats2half2_rn(o.x, o.y);
                __half2 p1 = __floats2half2_rn(o.z, o.w);
                uint2 st;
                st.x = *(unsigned*)&p0; st.y = *(unsigned*)&p1;
                *(uint2*)(out + (size_t)r * ldo + colOff + cg * 4) = st;
            }
        }
    }
}

// ================= aggregation (pull, fp16 rows, 8-deep pipelined gathers) =================
// s_i = g[i] + sum_{e in in(i)} g[col[e]]   (fp32 accumulate)
// MODE 0: out = relu(dinv*s + b)       MODE 1: out = dinv*s + b
// MODE 2: out = dinv*relu(dinv*s + b)  MODE 3: out = dinv^2*s   MODE 4: out = dinv*s
template <int WIDTH, int MODE>
__global__ __launch_bounds__(256) void k_agg(const __half* __restrict__ g, const int* __restrict__ rowptr,
                                             const int* __restrict__ col, const float* __restrict__ dinv,
                                             const float* __restrict__ bias, __half* __restrict__ out, int n) {
    constexpr int LPR = WIDTH / 8;   // lanes per row (8 or 16): 16B of fp16 per lane
    constexpr int RPW = 64 / LPR;    // rows per wave (8 or 4)
    int gw = (blockIdx.x * 256 + threadIdx.x) >> 6;
    int lane = threadIdx.x & 63;
    int seg = lane / LPR;
    int sl = lane % LPR;
    int row = gw * RPW + seg;
    if (row >= n) return;
    const uint4* g4 = (const uint4*)g + sl;   // 16B units; row stride = LPR units
    float acc[8];
    {
        uint4 s = g4[(size_t)row * LPR];  // self loop
        const __half2* h = (const __half2*)&s;
#pragma unroll
        for (int q = 0; q < 4; ++q) {
            float2 f = __half22float2(h[q]);
            acc[2 * q] = f.x; acc[2 * q + 1] = f.y;
        }
    }
    int e0 = rowptr[row], e1 = rowptr[row + 1];
    if (e0 < e1) {
        const int e1m1 = e1 - 1;
        int c[8];
#pragma unroll
        for (int j = 0; j < 8; ++j) c[j] = col[min(e0 + j, e1m1)];
        for (int eb = e0; eb < e1; eb += 8) {
            uint4 v[8];
#pragma unroll
            for (int j = 0; j < 8; ++j) v[j] = g4[(size_t)c[j] * LPR];
            int cn[8];
#pragma unroll
            for (int j = 0; j < 8; ++j) cn[j] = col[min(eb + 8 + j, e1m1)];
            int rem = e1 - eb;
#pragma unroll
            for (int j = 0; j < 8; ++j) {
                float m = (j < rem) ? 1.f : 0.f;
                const __half2* h = (const __half2*)&v[j];
#pragma unroll
                for (int q = 0; q < 4; ++q) {
                    float2 f = __half22float2(h[q]);
                    acc[2 * q]     = fmaf(m, f.x, acc[2 * q]);
                    acc[2 * q + 1] = fmaf(m, f.y, acc[2 * q + 1]);
                }
            }
#pragma unroll
            for (int j = 0; j < 8; ++j) c[j] = cn[j];
        }
    }
    float di = dinv[row];
    float r8[8];
    if (MODE == 0 || MODE == 1 || MODE == 2) {
        float4 b0 = *(const float4*)(bias + sl * 8);
        float4 b1 = *(const float4*)(bias + sl * 8 + 4);
        float bb[8] = {b0.x, b0.y, b0.z, b0.w, b1.x, b1.y, b1.z, b1.w};
#pragma unroll
        for (int t = 0; t < 8; ++t) {
            float s = di * acc[t] + bb[t];
            if (MODE == 0) r8[t] = fmaxf(s, 0.f);
            else if (MODE == 1) r8[t] = s;
            else r8[t] = di * fmaxf(s, 0.f);
        }
    } else if (MODE == 3) {
        float d2 = di * di;
#pragma unroll
        for (int t = 0; t < 8; ++t) r8[t] = acc[t] * d2;
    } else {
#pragma unroll
        for (int t = 0; t < 8; ++t) r8[t] = acc[t] * di;
    }
    uint4 o;
    __half2* oh = (__half2*)&o;
#pragma unroll
    for (int q = 0; q < 4; ++q) oh[q] = __floats2half2_rn(r8[2 * q], r8[2 * q + 1]);
    *((uint4*)out + (size_t)row * LPR + sl) = o;
}

// ================= global max pool (batch sorted) =================
__global__ __launch_bounds__(64) void k_pool(const float* __restrict__ z, const int* __restrict__ batch,
                                             unsigned* __restrict__ pooled, int n) {
    constexpr int ROWS = 128;
    int lane = threadIdx.x;
    int r0 = blockIdx.x * ROWS;
    if (r0 >= n) return;
    int r1 = min(r0 + ROWS, n);
    int cur = batch[r0];
    float m = -FLT_MAX;
    for (int r = r0; r < r1; ++r) {
        int b = batch[r];
        float v = z[(size_t)r * 64 + lane];
        if (b != cur) {
            atomicMax(&pooled[cur * 64 + lane], enc_ord(m));
            cur = b; m = v;
        } else {
            m = fmaxf(m, v);
        }
    }
    atomicMax(&pooled[cur * 64 + lane], enc_ord(m));
}

// ================= final MLP =================
__global__ __launch_bounds__(256) void k_mlp(const unsigned* __restrict__ pooled,
                                             const float* __restrict__ fc1w, const float* __restrict__ fc1b,
                                             const float* __restrict__ fc2w, const float* __restrict__ fc2b,
                                             const float* __restrict__ cpdw, const float* __restrict__ cpdb,
                                             const float* __restrict__ combw, const float* __restrict__ combb,
                                             float* __restrict__ out, int G) {
    __shared__ float s1[64 * 32], s2[32 * 16], sb1[32], sb2[16], scw[16], sow[16], shead[2];
    int tid = threadIdx.x;
    for (int i = tid; i < 2048; i += 256) s1[i] = fc1w[i];
    for (int i = tid; i < 512; i += 256) s2[i] = fc2w[i];
    if (tid < 32) sb1[tid] = fc1b[tid];
    if (tid < 16) { sb2[tid] = fc2b[tid]; scw[tid] = cpdw[tid]; sow[tid] = combw[tid]; }
    if (tid == 0) { shead[0] = cpdb[0]; shead[1] = combb[0]; }
    __syncthreads();
    if (tid < G) {
        float h0[64];
#pragma unroll
        for (int k = 0; k < 64; ++k) {
            unsigned u = pooled[tid * 64 + k];
            unsigned b = (u & 0x80000000u) ? (u & 0x7fffffffu) : ~u;
            h0[k] = __uint_as_float(b);
        }
        float h1[32];
#pragma unroll
        for (int j = 0; j < 32; ++j) {
            float a = sb1[j];
#pragma unroll
            for (int k = 0; k < 64; ++k) a += h0[k] * s1[k * 32 + j];
            h1[j] = fmaxf(a, 0.f);
        }
        float h2[16];
#pragma unroll
        for (int j = 0; j < 16; ++j) {
            float a = sb2[j];
#pragma unroll
            for (int k = 0; k < 32; ++k) a += h1[k] * s2[k * 16 + j];
            h2[j] = fmaxf(a, 0.f);
        }
        float c1 = shead[0], c2 = shead[1];
#pragma unroll
        for (int k = 0; k < 16; ++k) { c1 += h2[k] * scw[k]; c2 += h2[k] * sow[k]; }
        out[tid] = c1;
        out[G + tid] = c2;
    }
}

extern "C" void kernel_launch(void* const* d_in, const int* in_sizes, int n_in,
                              void* d_out, int out_size, void* d_ws, size_t ws_size,
                              hipStream_t stream) {
    const float* x      = (const float*)d_in[0];
    const int*   ei     = (const int*)d_in[1];
    const int*   batch  = (const int*)d_in[2];
    const float* enc_w1 = (const float*)d_in[3];
    const float* enc_b1 = (const float*)d_in[4];
    const float* enc_w2 = (const float*)d_in[5];
    const float* enc_b2 = (const float*)d_in[6];
    const float* w1 = (const float*)d_in[7];   const float* b1 = (const float*)d_in[8];
    const float* w2 = (const float*)d_in[9];   const float* b2 = (const float*)d_in[10];
    const float* w3 = (const float*)d_in[11];  const float* b3 = (const float*)d_in[12];
    const float* sgw = (const float*)d_in[13]; const float* sgb = (const float*)d_in[14];
    const float* fc1w = (const float*)d_in[15]; const float* fc1b = (const float*)d_in[16];
    const float* fc2w = (const float*)d_in[17]; const float* fc2b = (const float*)d_in[18];
    const float* cpdw = (const float*)d_in[19]; const float* cpdb = (const float*)d_in[20];
    const float* combw = (const float*)d_in[21]; const float* combb = (const float*)d_in[22];

    const int n = in_sizes[0] / 128;
    const int E = in_sizes[1] / 2;
    const int G = out_size / 2;
    const int nb = (n + 511) >> 9;
    float* outp = (float*)d_out;

    char* p = (char*)d_ws;
    auto alloc = [&](size_t bytes) -> char* {
        char* r = p;
        p += (bytes + 255) & ~(size_t)255;
        return r;
    };
    int* rowptr      = (int*)alloc((size_t)(n + 1) * 4);
    float* dinv      = (float*)alloc((size_t)n * 4);
    int* bcnt        = (int*)alloc(256 * 4);
    int* bbase       = (int*)alloc(257 * 4);
    int* bcur        = (int*)alloc(256 * 4);
    int* colA        = (int*)alloc((size_t)E * 4);
    unsigned* pooled = (unsigned*)alloc((size_t)G * 64 * 4);
    __half* A        = (__half*)alloc((size_t)n * 128 * 4);  // oversized: aliases pairs (E*8 bytes)
    __half* B        = (__half*)alloc((size_t)n * 128 * 2);
    float* Cf        = (float*)alloc((size_t)n * 64 * 4);
    int2* pairs      = (int2*)A;  // alias: pairs dead before first k_mm writes A

    hipMemsetAsync(bcnt, 0, 256 * 4, stream);
    hipMemsetAsync(pooled, 0, (size_t)G * 64 * 4, stream);

    const int gE = (E + 4095) / 4096;
    k_bcount<<<gE, 256, 0, stream>>>(ei + E, bcnt, E);
    k_bscan<<<1, 256, 0, stream>>>(bcnt, bbase, bcur, rowptr, nb, n, E);
    k_bscatter<<<gE, 256, 0, stream>>>(ei, bcur, pairs, E);
    k_bfill<<<nb, 512, 0, stream>>>(pairs, bbase, rowptr, dinv, colA, n);

    const int gm128 = (n + 31) / 32;
    const int gm64  = (n + 63) / 64;
    const int ga64  = (n + 31) / 32;   // 8 rows/wave, 4 waves/block
    const int ga128 = (n + 15) / 16;   // 4 rows/wave

    // encoder layer 1: x fp32 -> A fp16 (two column halves), propagate+relu
    k_mm<128, 64, true, false, float, __half><<<gm128, 256, 0, stream>>>(x, enc_w1, nullptr, dinv, A, n, 128, 128, 0);
    k_mm<128, 64, true, false, float, __half><<<gm128, 256, 0, stream>>>(x, enc_w1, nullptr, dinv, A, n, 128, 128, 64);
    k_agg<128, 0><<<ga128, 256, 0, stream>>>(A, rowptr, colA, dinv, enc_b1, B, n);
    // encoder layer 2: [N,128] fp16 -> [N,64] fp16
    k_mm<128, 64, true, false, __half, __half><<<gm128, 256, 0, stream>>>(B, enc_w2, nullptr, dinv, A, n, 64, 64, 0);
    k_agg<64, 1><<<ga64, 256, 0, stream>>>(A, rowptr, colA, dinv, enc_b2, B, n);
    // conv1, conv2
    k_mm<64, 64, true, false, __half, __half><<<gm64, 256, 0, stream>>>(B, w1, nullptr, dinv, A, n, 64, 64, 0);
    k_agg<64, 0><<<ga64, 256, 0, stream>>>(A, rowptr, colA, dinv, b1, B, n);
    k_mm<64, 64, true, false, __half, __half><<<gm64, 256, 0, stream>>>(B, w2, nullptr, dinv, A, n, 64, 64, 0);
    k_agg<64, 0><<<ga64, 256, 0, stream>>>(A, rowptr, colA, dinv, b2, B, n);
    // conv3 (output pre-scaled by dinv for SG chain)
    k_mm<64, 64, true, false, __half, __half><<<gm64, 256, 0, stream>>>(B, w3, nullptr, dinv, A, n, 64, 64, 0);
    k_agg<64, 2><<<ga64, 256, 0, stream>>>(A, rowptr, colA, dinv, b3, B, n);
    // SGConv K=4 propagates
    k_agg<64, 3><<<ga64, 256, 0, stream>>>(B, rowptr, colA, dinv, b3, A, n);
    k_agg<64, 3><<<ga64, 256, 0, stream>>>(A, rowptr, colA, dinv, b3, B, n);
    k_agg<64, 3><<<ga64, 256, 0, stream>>>(B, rowptr, colA, dinv, b3, A, n);
    k_agg<64, 4><<<ga64, 256, 0, stream>>>(A, rowptr, colA, dinv, b3, B, n);
    // SG linear -> fp32 for pool
    k_mm<64, 64, false, true, __half, float><<<gm64, 256, 0, stream>>>(B, sgw, sgb, dinv, Cf, n, 64, 64, 0);
    // pool + heads
    k_pool<<<(n + 127) / 128, 64, 0, stream>>>(Cf, batch, pooled, n);
    k_mlp<<<1, 256, 0, stream>>>(pooled, fc1w, fc1b, fc2w, fc2b, cpdw, cpdb, combw, combb, outp, G);
}